// Round 5
// baseline (389.105 us; speedup 1.0000x reference)
//
#include <hip/hip_runtime.h>
#include <hip/hip_bf16.h>

typedef __attribute__((ext_vector_type(8))) short bf16x8;   // 8 bf16 = 4 VGPRs
typedef __attribute__((ext_vector_type(4))) float f32x4;    // MFMA C/D frag, also 16B ld/st

#define Qn 4096
#define Mn 8192
#define Dn 128
#define NWA 4                    // waves per block
#define MSPLIT 4                 // M split across blockIdx.y
#define BCOLS (Mn / MSPLIT)      // 2048 cols per block
#define WCOLS (BCOLS / NWA)      // 512 cols per wave
#define NT 64                    // cols per iteration
#define NIT (WCOLS / NT)         // 8 iterations per wave

__device__ __forceinline__ unsigned short f2bf(float x) {
  __hip_bfloat16 h = __float2bfloat16(x);
  return *reinterpret_cast<unsigned short*>(&h);
}

__global__ void zero_kernel(float4* __restrict__ p, int n4) {
  int i = blockIdx.x * blockDim.x + threadIdx.x;
  if (i < n4) p[i] = make_float4(0.f, 0.f, 0.f, 0.f);
}

// Q * (1/sqrt(D)) -> bf16, vectorized
__global__ void cast_q(const float4* __restrict__ Q4, ushort4* __restrict__ Qs) {
  int i = blockIdx.x * blockDim.x + threadIdx.x;   // < Qn*Dn/4
  const float s = 0.088388347648318447f;           // 1/sqrt(128)
  float4 q = Q4[i];
  Qs[i] = make_ushort4(f2bf(q.x * s), f2bf(q.y * s), f2bf(q.z * s), f2bf(q.w * s));
}

// Swizzle K into MFMA-fragment-major bf16 layouts so the attn inner loop's
// B-fragment loads are contiguous 1KB per wave instruction:
//  Kswz (S=QK^T B-frag):  K[m][d] -> [((m>>4)*4 + (d>>5))*64 + lane][j]
//                         lane = ((d>>3)&3)*16 + (m&15), j = d&7
//  Vswz (PV B-frag, V^T): K[m][d] -> [(((m>>6)*8 + (d>>4))*2 + ((m&63)>>5))*64 + lane][j]
//                         lane = (((m&63)>>3)&3)*16 + (d&15), j = m&7
__global__ __launch_bounds__(256) void swz_kernel(const float* __restrict__ K,
                                                  unsigned short* __restrict__ Kswz,
                                                  unsigned short* __restrict__ Vswz) {
  __shared__ __align__(16) unsigned short T[64][72];   // 64m x 64d tile, bf16, padded
  const int m0 = blockIdx.x * 64, d0 = blockIdx.y * 64;
  const int t = threadIdx.x;
  const int r = t >> 4, c4 = (t & 15) * 4;
#pragma unroll
  for (int rr = 0; rr < 64; rr += 16) {
    float4 v = *reinterpret_cast<const float4*>(&K[(size_t)(m0 + r + rr) * Dn + d0 + c4]);
    ushort4 b = make_ushort4(f2bf(v.x), f2bf(v.y), f2bf(v.z), f2bf(v.w));
    *reinterpret_cast<ushort4*>(&T[r + rr][c4]) = b;
  }
  __syncthreads();
  // Kswz: per item (ml, oct): 8 d-consecutive shorts of one m-row
#pragma unroll
  for (int rep = 0; rep < 2; ++rep) {
    int w = t + rep * 256;
    int ml = w >> 3, oct = w & 7;
    uint4 val = *reinterpret_cast<uint4*>(&T[ml][oct * 8]);
    int m = m0 + ml, d = d0 + oct * 8;
    int g = m >> 4, l = m & 15, kk = d >> 5, quad = (d >> 3) & 3;
    *reinterpret_cast<uint4*>(&Kswz[(size_t)(((g * 4 + kk) * 64) + quad * 16 + l) * 8]) = val;
  }
  // Vswz: per item (dl, moct): 8 m-consecutive shorts of one d-column
#pragma unroll
  for (int rep = 0; rep < 2; ++rep) {
    int w = t + rep * 256;
    int dl = w >> 3, moct = w & 7;
    unsigned short tmp[8];
#pragma unroll
    for (int j = 0; j < 8; ++j) tmp[j] = T[moct * 8 + j][dl];
    int d = d0 + dl, m = m0 + moct * 8;
    int np = d >> 4, lB = d & 15, mt = m >> 6, mm = m & 63, kk2 = mm >> 5, qB = (mm >> 3) & 3;
    *reinterpret_cast<uint4*>(
        &Vswz[(size_t)((((mt * 8 + np) * 2 + kk2) * 64) + qB * 16 + lB) * 8]) =
        *reinterpret_cast<uint4*>(tmp);
  }
}

// One block: 16 Q-rows x 2048 M-cols. 4 waves split cols. No softmax-max
// rescaling: |logit| <= ~6 so exp() can't overflow; partials add linearly
// (global atomicAdd into Oacc/Lacc; finalize divides).
__global__ __launch_bounds__(256, 4)
void attn_kernel(const float* __restrict__ W,
                 const unsigned short* __restrict__ Qs,
                 const unsigned short* __restrict__ Kswz,
                 const unsigned short* __restrict__ Vswz,
                 float* __restrict__ Oacc,
                 float* __restrict__ Lacc) {
  __shared__ __align__(16) float Wlds[NWA][16][68];            // pad 64->68: rows 16B-aligned
  __shared__ __align__(16) unsigned short Plds[NWA][16][72];   // pad 64->72: 16B-aligned b128 reads
  __shared__ float Ored[16][Dn];
  __shared__ float lred[16];

  const int tid  = threadIdx.x;
  const int wave = tid >> 6;
  const int lane = tid & 63;
  const int l    = lane & 15;
  const int quad = lane >> 4;
  const int qb   = blockIdx.x * 16;
  const int mbeg = blockIdx.y * BCOLS + wave * WCOLS;

  for (int i = tid; i < 16 * Dn; i += 256) ((float*)Ored)[i] = 0.0f;
  if (tid < 16) lred[tid] = 0.0f;
  __syncthreads();

  // Persistent Q A-fragments: A[m=l][k=quad*8+j], kk=0..3 covers D=128.
  bf16x8 aq[4];
  {
    const unsigned short* qrow = Qs + (size_t)(qb + l) * Dn + quad * 8;
#pragma unroll
    for (int kk = 0; kk < 4; ++kk)
      aq[kk] = *reinterpret_cast<const bf16x8*>(qrow + 32 * kk);
  }

  f32x4 O[8];
#pragma unroll
  for (int n = 0; n < 8; ++n) O[n] = (f32x4){0.f, 0.f, 0.f, 0.f};
  float lsum[4] = {0.f, 0.f, 0.f, 0.f};

  // ---- W tile pipeline: 4x 16B nt global loads -> regs -> LDS ----
  const int wrow = lane >> 4;        // 0..3
  const int wcol = (lane & 15) * 4;  // 0..60
  f32x4 wA[4], wB[4];

#define LOADW(m0_, wr_)                                                          \
  {                                                                              \
    _Pragma("unroll") for (int j = 0; j < 4; ++j) (wr_)[j] =                     \
        __builtin_nontemporal_load(reinterpret_cast<const f32x4*>(               \
            &W[(size_t)(qb + j * 4 + wrow) * Mn + (m0_) + wcol]));               \
  }
#define WRITEW(wr_)                                                              \
  {                                                                              \
    _Pragma("unroll") for (int j = 0; j < 4; ++j)                                \
        *reinterpret_cast<f32x4*>(&Wlds[wave][j * 4 + wrow][wcol]) = (wr_)[j];   \
    asm volatile("s_waitcnt lgkmcnt(0)" ::: "memory");                           \
  }

  LOADW(mbeg, wA);            // W(0)
  LOADW(mbeg + NT, wB);       // W(1)
  WRITEW(wA);                 // Wlds <- W(0); waits only wA (wB stays in flight)

  // One iteration. Issue order: Kswz(16) -> Vswz(16, inside PV loop) ->
  // W(it+2) -> LDS-write W(it+1) [waits loads issued one full iter earlier].
#define ITER(it_, WLOAD_, WWRITE_)                                               \
  {                                                                              \
    const int m0 = mbeg + (it_) * NT;                                            \
    f32x4 S[4];                                                                  \
    _Pragma("unroll") for (int a = 0; a < 4; ++a)                                \
        S[a] = (f32x4){0.f, 0.f, 0.f, 0.f};                                      \
    _Pragma("unroll") for (int a = 0; a < 4; ++a) {                              \
      _Pragma("unroll") for (int kk = 0; kk < 4; ++kk) {                         \
        bf16x8 bk = *reinterpret_cast<const bf16x8*>(                            \
            Kswz + ((size_t)(((m0 >> 4) + a) * 4 + kk) * 64 + lane) * 8);        \
        S[a] = __builtin_amdgcn_mfma_f32_16x16x32_bf16(aq[kk], bk, S[a], 0, 0, 0);\
      }                                                                          \
    }                                                                            \
    _Pragma("unroll") for (int a = 0; a < 4; ++a) {                              \
      _Pragma("unroll") for (int r = 0; r < 4; ++r) {                            \
        float p = __expf(S[a][r] * Wlds[wave][quad * 4 + r][16 * a + l]);        \
        lsum[r] += p;                                                            \
        Plds[wave][quad * 4 + r][16 * a + l] = f2bf(p);                          \
      }                                                                          \
    }                                                                            \
    asm volatile("s_waitcnt lgkmcnt(0)" ::: "memory");                           \
    _Pragma("unroll") for (int kk = 0; kk < 2; ++kk) {                           \
      bf16x8 pa = *reinterpret_cast<const bf16x8*>(                              \
          &Plds[wave][l][32 * kk + quad * 8]);                                   \
      _Pragma("unroll") for (int n = 0; n < 8; ++n) {                            \
        bf16x8 bv = *reinterpret_cast<const bf16x8*>(                            \
            Vswz + ((size_t)(((m0 >> 6) * 8 + n) * 2 + kk) * 64 + lane) * 8);    \
        O[n] = __builtin_amdgcn_mfma_f32_16x16x32_bf16(pa, bv, O[n], 0, 0, 0);   \
      }                                                                          \
    }                                                                            \
    if ((it_) + 2 < NIT) LOADW(m0 + 2 * NT, WLOAD_);                             \
    if ((it_) + 1 < NIT) WRITEW(WWRITE_);                                        \
  }

  for (int it = 0; it < NIT; it += 2) {
    ITER(it, wA, wB);          // load W(it+2)->wA, publish W(it+1) from wB
    ITER(it + 1, wB, wA);      // load W(it+3)->wB, publish W(it+2) from wA
  }
#undef ITER
#undef LOADW
#undef WRITEW

  // Reduce lsum across the 16 lanes of each quad (cols live on l).
#pragma unroll
  for (int r = 0; r < 4; ++r)
#pragma unroll
    for (int off = 1; off < 16; off <<= 1)
      lsum[r] += __shfl_xor(lsum[r], off, 64);

  // Cross-wave combine in LDS (once per kernel; cheap).
#pragma unroll
  for (int n = 0; n < 8; ++n)
#pragma unroll
    for (int r = 0; r < 4; ++r)
      atomicAdd(&Ored[quad * 4 + r][16 * n + l], O[n][r]);
  if (l == 0)
#pragma unroll
    for (int r = 0; r < 4; ++r) atomicAdd(&lred[quad * 4 + r], lsum[r]);
  __syncthreads();

  // Cross-block combine via device atomics (R2-proven footprint).
  for (int i = tid; i < 16 * Dn; i += 256)
    atomicAdd(&Oacc[(size_t)qb * Dn + i], ((float*)Ored)[i]);
  if (tid < 16) atomicAdd(&Lacc[qb + tid], lred[tid]);
}

__global__ void finalize_kernel(const float4* __restrict__ Oacc,
                                const float* __restrict__ Lacc,
                                float4* __restrict__ out) {
  int i = blockIdx.x * blockDim.x + threadIdx.x;   // < Qn*Dn/4
  float4 o = Oacc[i];
  float inv = 1.0f / Lacc[i >> 5];                 // 32 float4 per row
  out[i] = make_float4(o.x * inv, o.y * inv, o.z * inv, o.w * inv);
}

extern "C" void kernel_launch(void* const* d_in, const int* in_sizes, int n_in,
                              void* d_out, int out_size, void* d_ws, size_t ws_size,
                              hipStream_t stream) {
  const float* Q = (const float*)d_in[0];          // [4096,128]
  const float* K = (const float*)d_in[1];          // [8192,128]
  const float* W = (const float*)d_in[2];          // [4096,8192]
  float* out = (float*)d_out;                      // [4096,128]

  unsigned short* Qs   = (unsigned short*)d_ws;               // 1 MB
  unsigned short* Kswz = Qs + (size_t)Qn * Dn;                // 2 MB
  unsigned short* Vswz = Kswz + (size_t)Mn * Dn;              // 2 MB
  float* Oacc = (float*)(Vswz + (size_t)Mn * Dn);             // 2 MB
  float* Lacc = Oacc + (size_t)Qn * Dn;                       // 16 KB (total 7.02 MB)

  int n4 = (Qn * Dn + Qn) / 4;                                // Oacc + Lacc zeroing
  zero_kernel<<<(n4 + 255) / 256, 256, 0, stream>>>((float4*)Oacc, n4);

  cast_q<<<(Qn * Dn / 4) / 256, 256, 0, stream>>>((const float4*)Q, (ushort4*)Qs);
  swz_kernel<<<dim3(Mn / 64, Dn / 64), 256, 0, stream>>>(K, Kswz, Vswz);
  attn_kernel<<<dim3(Qn / 16, MSPLIT), 256, 0, stream>>>(W, Qs, Kswz, Vswz, Oacc, Lacc);
  finalize_kernel<<<(Qn * Dn / 4) / 256, 256, 0, stream>>>(
      (const float4*)Oacc, Lacc, (float4*)out);
}

// Round 6
// 334.565 us; speedup vs baseline: 1.1630x; 1.1630x over previous
//
#include <hip/hip_runtime.h>
#include <hip/hip_bf16.h>

typedef __attribute__((ext_vector_type(8))) short bf16x8;   // 8 bf16 = 4 VGPRs
typedef __attribute__((ext_vector_type(4))) float f32x4;    // MFMA C/D frag

#define Qn 4096
#define Mn 8192
#define Dn 128
#define NWA 4                    // waves per block
#define MSPLIT 4                 // M split across blockIdx.y
#define BCOLS (Mn / MSPLIT)      // 2048 cols per block
#define WCOLS (BCOLS / NWA)      // 512 cols per wave
#define NT 64                    // cols per iteration
#define NIT (WCOLS / NT)         // 8 iterations per wave

__device__ __forceinline__ unsigned short f2bf(float x) {
  __hip_bfloat16 h = __float2bfloat16(x);
  return *reinterpret_cast<unsigned short*>(&h);
}

__global__ void zero_kernel(float4* __restrict__ p, int n4) {
  int i = blockIdx.x * blockDim.x + threadIdx.x;
  if (i < n4) p[i] = make_float4(0.f, 0.f, 0.f, 0.f);
}

// Q * (1/sqrt(D)) -> bf16, vectorized
__global__ void cast_q(const float4* __restrict__ Q4, ushort4* __restrict__ Qs) {
  int i = blockIdx.x * blockDim.x + threadIdx.x;   // < Qn*Dn/4
  const float s = 0.088388347648318447f;           // 1/sqrt(128)
  float4 q = Q4[i];
  Qs[i] = make_ushort4(f2bf(q.x * s), f2bf(q.y * s), f2bf(q.z * s), f2bf(q.w * s));
}

// Swizzle K into MFMA-fragment-major bf16 layouts so the attn inner loop's
// B-fragment loads are contiguous 1KB per wave instruction (proven R5):
//  Kswz (S=QK^T B-frag):  K[m][d] -> [((m>>4)*4 + (d>>5))*64 + lane][j]
//                         lane = ((d>>3)&3)*16 + (m&15), j = d&7
//  Vswz (PV B-frag, V^T): K[m][d] -> [(((m>>6)*8 + (d>>4))*2 + ((m&63)>>5))*64 + lane][j]
//                         lane = (((m&63)>>3)&3)*16 + (d&15), j = m&7
__global__ __launch_bounds__(256) void swz_kernel(const float* __restrict__ K,
                                                  unsigned short* __restrict__ Kswz,
                                                  unsigned short* __restrict__ Vswz) {
  __shared__ __align__(16) unsigned short T[64][72];   // 64m x 64d tile, bf16, padded
  const int m0 = blockIdx.x * 64, d0 = blockIdx.y * 64;
  const int t = threadIdx.x;
  const int r = t >> 4, c4 = (t & 15) * 4;
#pragma unroll
  for (int rr = 0; rr < 64; rr += 16) {
    float4 v = *reinterpret_cast<const float4*>(&K[(size_t)(m0 + r + rr) * Dn + d0 + c4]);
    ushort4 b = make_ushort4(f2bf(v.x), f2bf(v.y), f2bf(v.z), f2bf(v.w));
    *reinterpret_cast<ushort4*>(&T[r + rr][c4]) = b;
  }
  __syncthreads();
#pragma unroll
  for (int rep = 0; rep < 2; ++rep) {
    int w = t + rep * 256;
    int ml = w >> 3, oct = w & 7;
    uint4 val = *reinterpret_cast<uint4*>(&T[ml][oct * 8]);
    int m = m0 + ml, d = d0 + oct * 8;
    int g = m >> 4, l = m & 15, kk = d >> 5, quad = (d >> 3) & 3;
    *reinterpret_cast<uint4*>(&Kswz[(size_t)(((g * 4 + kk) * 64) + quad * 16 + l) * 8]) = val;
  }
#pragma unroll
  for (int rep = 0; rep < 2; ++rep) {
    int w = t + rep * 256;
    int dl = w >> 3, moct = w & 7;
    unsigned short tmp[8];
#pragma unroll
    for (int j = 0; j < 8; ++j) tmp[j] = T[moct * 8 + j][dl];
    int d = d0 + dl, m = m0 + moct * 8;
    int np = d >> 4, lB = d & 15, mt = m >> 6, mm = m & 63, kk2 = mm >> 5, qB = (mm >> 3) & 3;
    *reinterpret_cast<uint4*>(
        &Vswz[(size_t)((((mt * 8 + np) * 2 + kk2) * 64) + qB * 16 + lB) * 8]) =
        *reinterpret_cast<uint4*>(tmp);
  }
}

// One block: 16 Q-rows x 2048 M-cols. 4 waves split cols. No softmax-max
// rescaling: |logit| <= ~6 so exp() can't overflow; partials add linearly.
// waves_per_eu(3,3): pin 3 waves/SIMD -> 170-VGPR budget -> NO SPILLS
// (launch_bounds' min-only semantics let the compiler chase 8 waves/EU at
// 64 VGPRs and spill ~360 MB to scratch in R5).
__global__ __launch_bounds__(256) __attribute__((amdgpu_waves_per_eu(3, 3)))
void attn_kernel(const float* __restrict__ W,
                 const unsigned short* __restrict__ Qs,
                 const unsigned short* __restrict__ Kswz,
                 const unsigned short* __restrict__ Vswz,
                 float* __restrict__ Oacc,
                 float* __restrict__ Lacc) {
  __shared__ __align__(16) unsigned short Plds[NWA][16][72];   // pad 64->72: 16B-aligned b128 reads
  __shared__ float Ored[16][Dn];
  __shared__ float lred[16];

  const int tid  = threadIdx.x;
  const int wave = tid >> 6;
  const int lane = tid & 63;
  const int l    = lane & 15;
  const int quad = lane >> 4;
  const int qb   = blockIdx.x * 16;
  const int mbeg = blockIdx.y * BCOLS + wave * WCOLS;

  for (int i = tid; i < 16 * Dn; i += 256) ((float*)Ored)[i] = 0.0f;
  if (tid < 16) lred[tid] = 0.0f;
  __syncthreads();

  // Persistent Q A-fragments: A[m=l][k=quad*8+j], kk=0..3 covers D=128.
  bf16x8 aq[4];
  {
    const unsigned short* qrow = Qs + (size_t)(qb + l) * Dn + quad * 8;
#pragma unroll
    for (int kk = 0; kk < 4; ++kk)
      aq[kk] = *reinterpret_cast<const bf16x8*>(qrow + 32 * kk);
  }

  f32x4 O[8];
#pragma unroll
  for (int n = 0; n < 8; ++n) O[n] = (f32x4){0.f, 0.f, 0.f, 0.f};
  float lsum[4] = {0.f, 0.f, 0.f, 0.f};

  // W prefetch: per-lane scalar nt loads at the exact C-layout coordinates
  // the exp step consumes (row=qb+quad*4+r, col=m0+16a+l). Each instruction
  // is 4x64B segments -- line-coalesced. Two banks, distance-1 pipeline.
  float wA[16], wB[16];
#define LOADW(m0_, wr_)                                                          \
  {                                                                              \
    _Pragma("unroll") for (int a4 = 0; a4 < 4; ++a4)                             \
    _Pragma("unroll") for (int r4 = 0; r4 < 4; ++r4)                             \
        (wr_)[a4 * 4 + r4] = __builtin_nontemporal_load(                         \
            &W[(size_t)(qb + quad * 4 + r4) * Mn + (m0_) + 16 * a4 + l]);        \
  }

  LOADW(mbeg, wA);   // W(0)

  // Issue order per iter: Kswz(it) -> W(it+1) -> Vswz(it).
  // PV's wait on Vswz is a fine-grained vmcnt(N) that leaves W(it+1) in
  // flight; W(it+1) drains at S(it+1)'s Kswz wait -- a full iteration of
  // latency slack for the HBM-latency W stream.
#define ITER(it_, WCUR_, WNXT_)                                                  \
  {                                                                              \
    const int m0 = mbeg + (it_) * NT;                                            \
    f32x4 S[4];                                                                  \
    _Pragma("unroll") for (int a = 0; a < 4; ++a)                                \
        S[a] = (f32x4){0.f, 0.f, 0.f, 0.f};                                      \
    _Pragma("unroll") for (int a = 0; a < 4; ++a) {                              \
      _Pragma("unroll") for (int kk = 0; kk < 4; ++kk) {                         \
        bf16x8 bk = *reinterpret_cast<const bf16x8*>(                            \
            Kswz + ((size_t)(((m0 >> 4) + a) * 4 + kk) * 64 + lane) * 8);        \
        S[a] = __builtin_amdgcn_mfma_f32_16x16x32_bf16(aq[kk], bk, S[a], 0, 0, 0);\
      }                                                                          \
    }                                                                            \
    if ((it_) + 1 < NIT) LOADW(m0 + NT, WNXT_);                                  \
    _Pragma("unroll") for (int a = 0; a < 4; ++a) {                              \
      _Pragma("unroll") for (int r = 0; r < 4; ++r) {                            \
        float p = __expf(S[a][r] * (WCUR_)[a * 4 + r]);                          \
        lsum[r] += p;                                                            \
        Plds[wave][quad * 4 + r][16 * a + l] = f2bf(p);                          \
      }                                                                          \
    }                                                                            \
    asm volatile("s_waitcnt lgkmcnt(0)" ::: "memory");                           \
    _Pragma("unroll") for (int kk = 0; kk < 2; ++kk) {                           \
      bf16x8 pa = *reinterpret_cast<const bf16x8*>(                              \
          &Plds[wave][l][32 * kk + quad * 8]);                                   \
      _Pragma("unroll") for (int n = 0; n < 8; ++n) {                            \
        bf16x8 bv = *reinterpret_cast<const bf16x8*>(                            \
            Vswz + ((size_t)(((m0 >> 6) * 8 + n) * 2 + kk) * 64 + lane) * 8);    \
        O[n] = __builtin_amdgcn_mfma_f32_16x16x32_bf16(pa, bv, O[n], 0, 0, 0);   \
      }                                                                          \
    }                                                                            \
  }

  for (int it = 0; it < NIT; it += 2) {
    ITER(it, wA, wB);          // consume W(it) from wA, prefetch W(it+1)->wB
    ITER(it + 1, wB, wA);      // consume from wB, prefetch ->wA
  }
#undef ITER
#undef LOADW

  // Reduce lsum across the 16 lanes of each quad (cols live on l).
#pragma unroll
  for (int r = 0; r < 4; ++r)
#pragma unroll
    for (int off = 1; off < 16; off <<= 1)
      lsum[r] += __shfl_xor(lsum[r], off, 64);

  // Cross-wave combine in LDS (once per kernel; cheap).
#pragma unroll
  for (int n = 0; n < 8; ++n)
#pragma unroll
    for (int r = 0; r < 4; ++r)
      atomicAdd(&Ored[quad * 4 + r][16 * n + l], O[n][r]);
  if (l == 0)
#pragma unroll
    for (int r = 0; r < 4; ++r) atomicAdd(&lred[quad * 4 + r], lsum[r]);
  __syncthreads();

  // Cross-block combine via device atomics (R2/R5-proven footprint).
  for (int i = tid; i < 16 * Dn; i += 256)
    atomicAdd(&Oacc[(size_t)qb * Dn + i], ((float*)Ored)[i]);
  if (tid < 16) atomicAdd(&Lacc[qb + tid], lred[tid]);
}

__global__ void finalize_kernel(const float4* __restrict__ Oacc,
                                const float* __restrict__ Lacc,
                                float4* __restrict__ out) {
  int i = blockIdx.x * blockDim.x + threadIdx.x;   // < Qn*Dn/4
  float4 o = Oacc[i];
  float inv = 1.0f / Lacc[i >> 5];                 // 32 float4 per row
  out[i] = make_float4(o.x * inv, o.y * inv, o.z * inv, o.w * inv);
}

extern "C" void kernel_launch(void* const* d_in, const int* in_sizes, int n_in,
                              void* d_out, int out_size, void* d_ws, size_t ws_size,
                              hipStream_t stream) {
  const float* Q = (const float*)d_in[0];          // [4096,128]
  const float* K = (const float*)d_in[1];          // [8192,128]
  const float* W = (const float*)d_in[2];          // [4096,8192]
  float* out = (float*)d_out;                      // [4096,128]

  unsigned short* Qs   = (unsigned short*)d_ws;               // 1 MB
  unsigned short* Kswz = Qs + (size_t)Qn * Dn;                // 2 MB
  unsigned short* Vswz = Kswz + (size_t)Mn * Dn;              // 2 MB
  float* Oacc = (float*)(Vswz + (size_t)Mn * Dn);             // 2 MB
  float* Lacc = Oacc + (size_t)Qn * Dn;                       // 16 KB (total 7.02 MB)

  int n4 = (Qn * Dn + Qn) / 4;                                // Oacc + Lacc zeroing
  zero_kernel<<<(n4 + 255) / 256, 256, 0, stream>>>((float4*)Oacc, n4);

  cast_q<<<(Qn * Dn / 4) / 256, 256, 0, stream>>>((const float4*)Q, (ushort4*)Qs);
  swz_kernel<<<dim3(Mn / 64, Dn / 64), 256, 0, stream>>>(K, Kswz, Vswz);
  attn_kernel<<<dim3(Qn / 16, MSPLIT), 256, 0, stream>>>(W, Qs, Kswz, Vswz, Oacc, Lacc);
  finalize_kernel<<<(Qn * Dn / 4) / 256, 256, 0, stream>>>(
      (const float4*)Oacc, Lacc, (float4*)out);
}